// Round 4
// baseline (731.369 us; speedup 1.0000x reference)
//
#include <hip/hip_runtime.h>
#include <hip/hip_bf16.h>

#define CCH 512
#define BATCH 8
#define TLEN 8192
#define RPITCH ((size_t)TLEN * CCH)   // per-batch pitch for t-major bf16 bufs

using f32x4 = __attribute__((ext_vector_type(4))) float;
using s16x8 = __attribute__((ext_vector_type(8))) short;
using s16x4 = __attribute__((ext_vector_type(4))) short;
using s16x2 = __attribute__((ext_vector_type(2))) short;

__device__ __forceinline__ float b2f(short s) {
    union { unsigned int i; float f; } u; u.i = ((unsigned int)(unsigned short)s) << 16; return u.f;
}
__device__ __forceinline__ short f2b(float f) {
    __hip_bfloat16 h = __float2bfloat16(f);
    return *reinterpret_cast<short*>(&h);
}

__device__ __forceinline__ void glds16(const void* g, void* l) {
    __builtin_amdgcn_global_load_lds(
        (const __attribute__((address_space(1))) unsigned int*)g,
        (__attribute__((address_space(3))) unsigned int*)l, 16, 0, 0);
}

// ---------------------------------------------------------------------------
// Weight norm + bf16 pack into chunk-major MFMA layout WITH the T2 swizzle
// baked into the global image (global->LDS copy is linear, LDS inherits it):
//   dest[((ci>>5)*4 + (co>>7))*3 + tap][row=co&127][(ci&31) ^ ((row>>1)&3)<<3]
// ---------------------------------------------------------------------------
__global__ __launch_bounds__(256) void wn_pack_kernel(const float* __restrict__ v,
                                                      const float* __restrict__ g,
                                                      short* __restrict__ wp)
{
    int co = blockIdx.x;
    const float* vr = v + (size_t)co * (CCH * 3);
    float s = 0.f;
    for (int i = threadIdx.x; i < CCH * 3; i += 256) { float xv = vr[i]; s += xv * xv; }
#pragma unroll
    for (int off = 32; off > 0; off >>= 1) s += __shfl_down(s, off);
    __shared__ float red[4];
    int lane = threadIdx.x & 63, wv = threadIdx.x >> 6;
    if (lane == 0) red[wv] = s;
    __syncthreads();
    float tot = red[0] + red[1] + red[2] + red[3];
    float scale = g[co] / sqrtf(tot);
    int row = co & 127;
    int swz = ((row >> 1) & 3) << 3;
    for (int i = threadIdx.x; i < CCH * 3; i += 256) {
        int ci = i / 3, tap = i - ci * 3;
        size_t dst = ((size_t)(((ci >> 5) * 4 + (co >> 7)) * 3 + tap)) * 4096
                     + (size_t)row * 32 + ((ci & 31) ^ swz);
        wp[dst] = f2b(vr[i] * scale);
    }
}

// ---------------------------------------------------------------------------
// Transpose x fp32 [b][c][8192] -> bf16 t-major [b][8192][512]
// ---------------------------------------------------------------------------
__global__ __launch_bounds__(256) void transpose_kernel2(const float* __restrict__ x,
                                                         short* __restrict__ out)
{
    __shared__ float ls[64][65];
    int tid = threadIdx.x;
    int t0 = blockIdx.x * 64, c0 = blockIdx.y * 64, b = blockIdx.z;
    const float* xb = x + (size_t)b * CCH * TLEN;
#pragma unroll
    for (int p = 0; p < 4; ++p) {
        int c = p * 16 + (tid >> 4);
        int t4 = (tid & 15) * 4;
        f32x4 v = *(const f32x4*)&xb[(size_t)(c0 + c) * TLEN + t0 + t4];
#pragma unroll
        for (int i = 0; i < 4; ++i) ls[c][t4 + i] = v[i];
    }
    __syncthreads();
    short* ob = out + (size_t)b * RPITCH;
#pragma unroll
    for (int p = 0; p < 4; ++p) {
        int t = p * 16 + (tid >> 4);
        int c4 = (tid & 15) * 4;
        s16x4 o;
#pragma unroll
        for (int i = 0; i < 4; ++i) o[i] = f2b(ls[c4 + i][t]);
        *(s16x4*)(ob + (size_t)(t0 + t) * CCH + c0 + c4) = o;
    }
}

// ---------------------------------------------------------------------------
// Fused activation1d on t-major layout; 2 channels per lane, ALT=64,
// prefetch distance 3.  (Measured ~50us better than ALT=128 pipeline-wide.)
// ---------------------------------------------------------------------------
#define ALT 64
__global__ __launch_bounds__(256, 4) void act_kernel(
    const short* __restrict__ in, short* __restrict__ out,
    const float* __restrict__ alpha, const float* __restrict__ beta,
    const float* __restrict__ upf, const float* __restrict__ dwf,
    int Tin, int Tout)
{
    int tid = threadIdx.x;
    int c2 = tid * 2;
    int b = blockIdx.z;
    int t0 = blockIdx.x * ALT;
    const short* ib = in + (size_t)b * RPITCH + c2;
    short* ob = out + (size_t)b * RPITCH + c2;

    float ph0[6], ph1[6], fw[12];
#pragma unroll
    for (int m = 0; m < 6; ++m) { ph0[m] = upf[m]; ph1[m] = upf[6 + m]; }
#pragma unroll
    for (int k = 0; k < 12; ++k) fw[k] = dwf[k];

    float twoa[2], inv2b[2];
#pragma unroll
    for (int ch = 0; ch < 2; ++ch) {
        twoa[ch]  = 2.f * __expf(alpha[c2 + ch]);
        inv2b[ch] = 1.f / (2.f * __expf(beta[c2 + ch]) + 1e-9f);
    }
    int Ls = 2 * Tin - 4;

    auto ldx2 = [&](int t, float* dst) {
        if (t >= 0 && t < Tin) {
            s16x2 v = *(const s16x2*)(ib + (size_t)t * CCH);
            dst[0] = b2f(v[0]); dst[1] = b2f(v[1]);
        } else { dst[0] = 0.f; dst[1] = 0.f; }
    };

    float xa[12][2];
#pragma unroll
    for (int i = 0; i < 12; ++i) ldx2(t0 - 4 + i, xa[i]);
    float sr[12][2];
#pragma unroll
    for (int i = 0; i < 12; ++i) {
        int j = 2 * t0 - 5 + i;
        int xoff = ((i - 3) >> 1) + 2;
        const float* ph = ((i + 1) & 1) ? ph1 : ph0;
        bool ok = (j >= 0 && j < Ls);
#pragma unroll
        for (int ch = 0; ch < 2; ++ch) {
            float u = 0.f;
#pragma unroll
            for (int m = 0; m < 6; ++m) u += ph[m] * xa[xoff + m][ch];
            sr[i][ch] = ok ? (u + (1.f - __cosf(twoa[ch] * u)) * inv2b[ch]) : 0.f;
        }
    }
    float xw[9][2];
#pragma unroll
    for (int m = 0; m < 6; ++m) { xw[m][0] = xa[6 + m][0]; xw[m][1] = xa[6 + m][1]; }
    ldx2(t0 + 8,  xw[6]);
    ldx2(t0 + 9,  xw[7]);
    ldx2(t0 + 10, xw[8]);

#pragma unroll 4
    for (int it = 0; it < ALT; ++it) {
        int t = t0 + it;
        float y[2] = {0.f, 0.f};
#pragma unroll
        for (int k = 0; k < 12; ++k) {
            y[0] += fw[k] * sr[k][0];
            y[1] += fw[k] * sr[k][1];
        }
        if (t < Tout) {
            s16x2 o; o[0] = f2b(y[0]); o[1] = f2b(y[1]);
            *(s16x2*)(ob + (size_t)t * CCH) = o;
        }
        bool ok1 = (2 * t + 7 < Ls), ok2 = (2 * t + 8 < Ls);
        float s1[2], s2[2];
#pragma unroll
        for (int ch = 0; ch < 2; ++ch) {
            float u1 = 0.f, u2 = 0.f;
#pragma unroll
            for (int m = 0; m < 6; ++m) {
                u1 += ph1[m] * xw[m][ch];
                u2 += ph0[m] * xw[m + 1][ch];
            }
            s1[ch] = ok1 ? (u1 + (1.f - __cosf(twoa[ch] * u1)) * inv2b[ch]) : 0.f;
            s2[ch] = ok2 ? (u2 + (1.f - __cosf(twoa[ch] * u2)) * inv2b[ch]) : 0.f;
        }
#pragma unroll
        for (int i = 0; i < 10; ++i) { sr[i][0] = sr[i + 2][0]; sr[i][1] = sr[i + 2][1]; }
        sr[10][0] = s1[0]; sr[10][1] = s1[1];
        sr[11][0] = s2[0]; sr[11][1] = s2[1];
#pragma unroll
        for (int m = 0; m < 8; ++m) { xw[m][0] = xw[m + 1][0]; xw[m][1] = xw[m + 1][1]; }
        ldx2(t + 11, xw[8]);   // 3-iteration prefetch distance
    }
}

// ---------------------------------------------------------------------------
// MFMA conv1d (k=3, pad=1) on t-major bf16 input, 128co x 256t tile.
// 4 waves (2 wm x 2 wn), wave = 64co x 128t = 4x8 frags of 16x16x32.
// R1's proven structure (gload_lds staging, issue-at-top / drain-at-end,
// __syncthreads per cc) with 2x the MFMA per barrier: ~1860 cyc compute
// per iteration fully covers HBM latency; weight L2 refetch halves
// (1024 blocks instead of 2048).  1 block/CU (LDS 82KB) by design.
// T2 swizzle on both tiles (involution s ^ ((s>>3)&3) on 16B slots,
// row-preserving; weights pre-swizzled in global by wn_pack).
// ---------------------------------------------------------------------------
template <int MODE>
__global__ __launch_bounds__(256, 1) void conv_mfma(
    const short* __restrict__ xin, const short* __restrict__ wp,
    const float* __restrict__ bias, const float* __restrict__ resid,
    float* __restrict__ outF, short* __restrict__ outT, int rows)
{
    constexpr int WB = 3 * 128 * 32;   // 12288 shorts (24576 B) weights/chunk
    constexpr int IB = 260 * 32;       // 8320 shorts (16640 B) input rows
    constexpr int PB = WB + IB;        // 20608 shorts
    __shared__ __align__(16) short lds[2 * PB];   // 82432 B

    int tid = threadIdx.x;
    int wave = tid >> 6, lane = tid & 63;
    int quad = lane >> 4, l16 = lane & 15;
    int wm = wave >> 1, wn = wave & 1;
    int bx = blockIdx.x;
    int cog = bx & 3, tt = bx >> 2;
    int t0 = tt * 256, b = blockIdx.z;

    const short* inb = xin + (size_t)b * RPITCH;
    bool interior = (t0 >= 1) && (t0 + 259 <= rows);

    auto stage = [&](int cc, int pb) {
        short* base = lds + pb * PB;
        short* wl = base;
        short* il = base + WB;
        const short* wsrc = wp + (size_t)(cc * 4 + cog) * WB;
#pragma unroll
        for (int p = 0; p < 6; ++p) {
            int seg = wave * 6 + p;
            glds16(wsrc + seg * 512 + lane * 8, wl + seg * 512);
        }
        const short* isrc = inb + (size_t)(t0 - 1) * CCH + cc * 32;
        if (interior) {
#pragma unroll
            for (int p = 0; p < 4; ++p) {
                int sg = wave * 4 + p;
                int s = sg * 64 + lane;         // linear physical 16B slot
                int u = s ^ ((s >> 3) & 3);     // logical slot (inverse swizzle)
                glds16(isrc + (size_t)(u >> 2) * CCH + (u & 3) * 8, il + sg * 512);
            }
            if (wave == 0 && lane < 16) {
                int s = 1024 + lane;
                int u = s ^ ((s >> 3) & 3);
                glds16(isrc + (size_t)(u >> 2) * CCH + (u & 3) * 8, il + 1024 * 8);
            }
        } else {
            for (int s = tid; s < 1040; s += 256) {
                int gt = t0 - 1 + (s >> 2);     // swizzle preserves row
                s16x8 v = 0;
                if (gt >= 0 && gt < rows)
                    v = *(const s16x8*)(inb + (size_t)gt * CCH + cc * 32 + (s & 3) * 8);
                int ps = s ^ ((s >> 3) & 3);
                *(s16x8*)(il + ps * 8) = v;
            }
        }
    };

    f32x4 acc[4][8];
#pragma unroll
    for (int i = 0; i < 4; ++i)
#pragma unroll
        for (int j = 0; j < 8; ++j) acc[i][j] = 0.f;

    auto compute = [&](int pb) {
        const short* base = lds + pb * PB;
        const short* wl = base;
        const short* il = base + WB;
        __builtin_amdgcn_s_setprio(1);
#pragma unroll
        for (int tap = 0; tap < 3; ++tap) {
            s16x8 af[4], bv[8];
#pragma unroll
            for (int mf = 0; mf < 4; ++mf) {
                int row = wm * 64 + mf * 16 + l16;
                int off = (quad * 8) ^ (((row >> 1) & 3) << 3);
                af[mf] = *(const s16x8*)(wl + tap * 4096 + row * 32 + off);
            }
#pragma unroll
            for (int nf = 0; nf < 8; ++nf) {
                int row = wn * 128 + nf * 16 + l16 + tap;
                int off = (quad * 8) ^ (((row >> 1) & 3) << 3);
                bv[nf] = *(const s16x8*)(il + row * 32 + off);
            }
#pragma unroll
            for (int mf = 0; mf < 4; ++mf)
#pragma unroll
                for (int nf = 0; nf < 8; ++nf)
                    acc[mf][nf] = __builtin_amdgcn_mfma_f32_16x16x32_bf16(
                        af[mf], bv[nf], acc[mf][nf], 0, 0, 0);
        }
        __builtin_amdgcn_s_setprio(0);
    };

    stage(0, 0);
    __syncthreads();

    for (int cc = 0; cc < 16; ++cc) {
        if (cc < 15) stage(cc + 1, (cc + 1) & 1);   // issue early
        compute(cc & 1);
        __syncthreads();                             // drain late (loads had full compute)
    }

    f32x4 b4[4];
#pragma unroll
    for (int mf = 0; mf < 4; ++mf)
        b4[mf] = *(const f32x4*)(bias + cog * 128 + wm * 64 + mf * 16 + quad * 4);

    if (MODE == 0) {
        // Stage bf16 tile [t 256][co 128] (pitch 136) then coalesced stores.
        short* ot = lds;
#pragma unroll
        for (int mf = 0; mf < 4; ++mf)
#pragma unroll
            for (int nf = 0; nf < 8; ++nf) {
                int t = wn * 128 + nf * 16 + l16;
                int co = wm * 64 + mf * 16 + quad * 4;
                s16x4 o;
#pragma unroll
                for (int r = 0; r < 4; ++r) o[r] = f2b(acc[mf][nf][r] + b4[mf][r]);
                *(s16x4*)(ot + t * 136 + co) = o;
            }
        __syncthreads();
#pragma unroll
        for (int rr = 0; rr < 16; ++rr) {
            int idx = rr * 256 + tid;
            int tr = idx >> 4, c8 = (idx & 15) * 8;
            int t = t0 + tr;
            if (t < rows)
                *(s16x8*)(outT + (size_t)b * RPITCH + (size_t)t * CCH + cog * 128 + c8)
                    = *(const s16x8*)(ot + tr * 136 + c8);
        }
    } else {
        // Two halves of fp32 [co 64][t 256] (pitch 260), +bias then +residual.
        float* of = (float*)lds;
#pragma unroll
        for (int h = 0; h < 2; ++h) {
            if (wm == h) {
#pragma unroll
                for (int mf = 0; mf < 4; ++mf)
#pragma unroll
                    for (int nf = 0; nf < 8; ++nf) {
                        int t = wn * 128 + nf * 16 + l16;
#pragma unroll
                        for (int r = 0; r < 4; ++r)
                            of[(mf * 16 + quad * 4 + r) * 260 + t] = acc[mf][nf][r] + b4[mf][r];
                    }
            }
            __syncthreads();
#pragma unroll
            for (int rr = 0; rr < 16; ++rr) {
                int idx = rr * 256 + tid;
                int row = idx >> 6, c4 = (idx & 63) * 4;
                int co = cog * 128 + h * 64 + row;
                int t = t0 + c4;
                f32x4 v = *(const f32x4*)(of + row * 260 + c4);
                size_t ro = (size_t)b * CCH + co;
                const float* rrow = resid + ro * TLEN;
                float* orow = outF + ro * (size_t)rows;
                if (t + 3 < rows) {
                    f32x4 rv = *(const f32x4*)(rrow + t);
                    f32x4 ov;
#pragma unroll
                    for (int i = 0; i < 4; ++i) ov[i] = v[i] + rv[i];
                    *(f32x4*)(orow + t) = ov;
                } else {
#pragma unroll
                    for (int i = 0; i < 4; ++i)
                        if (t + i < rows) orow[t + i] = v[i] + rrow[t + i];
                }
            }
            __syncthreads();
        }
    }
}

// ---------------------------------------------------------------------------
extern "C" void kernel_launch(void* const* d_in, const int* in_sizes, int n_in,
                              void* d_out, int out_size, void* d_ws, size_t ws_size,
                              hipStream_t stream)
{
    const float* x      = (const float*)d_in[0];
    const float* alpha1 = (const float*)d_in[1];
    const float* beta1  = (const float*)d_in[2];
    const float* alpha2 = (const float*)d_in[3];
    const float* beta2  = (const float*)d_in[4];
    const float* v1     = (const float*)d_in[5];
    const float* g1     = (const float*)d_in[6];
    const float* b1     = (const float*)d_in[7];
    const float* v2     = (const float*)d_in[8];
    const float* g2     = (const float*)d_in[9];
    const float* b2     = (const float*)d_in[10];
    const float* upf    = (const float*)d_in[11];
    const float* dwf    = (const float*)d_in[12];
    float* out = (float*)d_out;

    const int T1 = TLEN - 2;  // 8190
    const int T2 = TLEN - 4;  // 8188

    char* wsb = (char*)d_ws;
    short* w1p = (short*)wsb;
    short* w2p = w1p + (size_t)CCH * CCH * 3;
    short* bufX = w2p + (size_t)CCH * CCH * 3;
    short* bufY = bufX + (size_t)BATCH * RPITCH;

    wn_pack_kernel<<<CCH, 256, 0, stream>>>(v1, g1, w1p);
    wn_pack_kernel<<<CCH, 256, 0, stream>>>(v2, g2, w2p);

    transpose_kernel2<<<dim3(TLEN / 64, CCH / 64, BATCH), 256, 0, stream>>>(x, bufX);

    act_kernel<<<dim3((TLEN + ALT - 1) / ALT, 1, BATCH), 256, 0, stream>>>(
        bufX, bufY, alpha1, beta1, upf, dwf, TLEN, T1);

    conv_mfma<0><<<dim3(4 * 32, 1, BATCH), 256, 0, stream>>>(
        bufY, w1p, b1, nullptr, nullptr, bufX, T1);

    act_kernel<<<dim3((T1 + ALT - 1) / ALT, 1, BATCH), 256, 0, stream>>>(
        bufX, bufY, alpha2, beta2, upf, dwf, T1, T2);

    conv_mfma<1><<<dim3(4 * 32, 1, BATCH), 256, 0, stream>>>(
        bufY, w2p, b2, x, out, nullptr, T2);
}

// Round 5
// 615.527 us; speedup vs baseline: 1.1882x; 1.1882x over previous
//
#include <hip/hip_runtime.h>
#include <hip/hip_bf16.h>

#define CCH 512
#define BATCH 8
#define TLEN 8192
#define RPITCH ((size_t)TLEN * CCH)   // per-batch pitch for t-major bf16 bufs

using f32x4 = __attribute__((ext_vector_type(4))) float;
using s16x8 = __attribute__((ext_vector_type(8))) short;
using s16x4 = __attribute__((ext_vector_type(4))) short;
using s16x2 = __attribute__((ext_vector_type(2))) short;

__device__ __forceinline__ float b2f(short s) {
    union { unsigned int i; float f; } u; u.i = ((unsigned int)(unsigned short)s) << 16; return u.f;
}
__device__ __forceinline__ short f2b(float f) {
    __hip_bfloat16 h = __float2bfloat16(f);
    return *reinterpret_cast<short*>(&h);
}

__device__ __forceinline__ void glds16(const void* g, void* l) {
    __builtin_amdgcn_global_load_lds(
        (const __attribute__((address_space(1))) unsigned int*)g,
        (__attribute__((address_space(3))) unsigned int*)l, 16, 0, 0);
}

// ---------------------------------------------------------------------------
// Weight norm + bf16 pack into chunk-major MFMA layout WITH the T2 swizzle
// baked into the global image (global->LDS copy is linear, LDS inherits it):
//   dest[((ci>>5)*4 + (co>>7))*3 + tap][row=co&127][(ci&31) ^ ((row>>1)&3)<<3]
// ---------------------------------------------------------------------------
__global__ __launch_bounds__(256) void wn_pack_kernel(const float* __restrict__ v,
                                                      const float* __restrict__ g,
                                                      short* __restrict__ wp)
{
    int co = blockIdx.x;
    const float* vr = v + (size_t)co * (CCH * 3);
    float s = 0.f;
    for (int i = threadIdx.x; i < CCH * 3; i += 256) { float xv = vr[i]; s += xv * xv; }
#pragma unroll
    for (int off = 32; off > 0; off >>= 1) s += __shfl_down(s, off);
    __shared__ float red[4];
    int lane = threadIdx.x & 63, wv = threadIdx.x >> 6;
    if (lane == 0) red[wv] = s;
    __syncthreads();
    float tot = red[0] + red[1] + red[2] + red[3];
    float scale = g[co] / sqrtf(tot);
    int row = co & 127;
    int swz = ((row >> 1) & 3) << 3;
    for (int i = threadIdx.x; i < CCH * 3; i += 256) {
        int ci = i / 3, tap = i - ci * 3;
        size_t dst = ((size_t)(((ci >> 5) * 4 + (co >> 7)) * 3 + tap)) * 4096
                     + (size_t)row * 32 + ((ci & 31) ^ swz);
        wp[dst] = f2b(vr[i] * scale);
    }
}

// ---------------------------------------------------------------------------
// Transpose x fp32 [b][c][8192] -> bf16 t-major [b][8192][512]
// ---------------------------------------------------------------------------
__global__ __launch_bounds__(256) void transpose_kernel2(const float* __restrict__ x,
                                                         short* __restrict__ out)
{
    __shared__ float ls[64][65];
    int tid = threadIdx.x;
    int t0 = blockIdx.x * 64, c0 = blockIdx.y * 64, b = blockIdx.z;
    const float* xb = x + (size_t)b * CCH * TLEN;
#pragma unroll
    for (int p = 0; p < 4; ++p) {
        int c = p * 16 + (tid >> 4);
        int t4 = (tid & 15) * 4;
        f32x4 v = *(const f32x4*)&xb[(size_t)(c0 + c) * TLEN + t0 + t4];
#pragma unroll
        for (int i = 0; i < 4; ++i) ls[c][t4 + i] = v[i];
    }
    __syncthreads();
    short* ob = out + (size_t)b * RPITCH;
#pragma unroll
    for (int p = 0; p < 4; ++p) {
        int t = p * 16 + (tid >> 4);
        int c4 = (tid & 15) * 4;
        s16x4 o;
#pragma unroll
        for (int i = 0; i < 4; ++i) o[i] = f2b(ls[c4 + i][t]);
        *(s16x4*)(ob + (size_t)(t0 + t) * CCH + c0 + c4) = o;
    }
}

// ---------------------------------------------------------------------------
// Fused activation1d on t-major layout; 2 channels per lane, ALT=64,
// prefetch distance 3.  (Measured ~50us better than ALT=128 pipeline-wide.)
// ---------------------------------------------------------------------------
#define ALT 64
__global__ __launch_bounds__(256, 4) void act_kernel(
    const short* __restrict__ in, short* __restrict__ out,
    const float* __restrict__ alpha, const float* __restrict__ beta,
    const float* __restrict__ upf, const float* __restrict__ dwf,
    int Tin, int Tout)
{
    int tid = threadIdx.x;
    int c2 = tid * 2;
    int b = blockIdx.z;
    int t0 = blockIdx.x * ALT;
    const short* ib = in + (size_t)b * RPITCH + c2;
    short* ob = out + (size_t)b * RPITCH + c2;

    float ph0[6], ph1[6], fw[12];
#pragma unroll
    for (int m = 0; m < 6; ++m) { ph0[m] = upf[m]; ph1[m] = upf[6 + m]; }
#pragma unroll
    for (int k = 0; k < 12; ++k) fw[k] = dwf[k];

    float twoa[2], inv2b[2];
#pragma unroll
    for (int ch = 0; ch < 2; ++ch) {
        twoa[ch]  = 2.f * __expf(alpha[c2 + ch]);
        inv2b[ch] = 1.f / (2.f * __expf(beta[c2 + ch]) + 1e-9f);
    }
    int Ls = 2 * Tin - 4;

    auto ldx2 = [&](int t, float* dst) {
        if (t >= 0 && t < Tin) {
            s16x2 v = *(const s16x2*)(ib + (size_t)t * CCH);
            dst[0] = b2f(v[0]); dst[1] = b2f(v[1]);
        } else { dst[0] = 0.f; dst[1] = 0.f; }
    };

    float xa[12][2];
#pragma unroll
    for (int i = 0; i < 12; ++i) ldx2(t0 - 4 + i, xa[i]);
    float sr[12][2];
#pragma unroll
    for (int i = 0; i < 12; ++i) {
        int j = 2 * t0 - 5 + i;
        int xoff = ((i - 3) >> 1) + 2;
        const float* ph = ((i + 1) & 1) ? ph1 : ph0;
        bool ok = (j >= 0 && j < Ls);
#pragma unroll
        for (int ch = 0; ch < 2; ++ch) {
            float u = 0.f;
#pragma unroll
            for (int m = 0; m < 6; ++m) u += ph[m] * xa[xoff + m][ch];
            sr[i][ch] = ok ? (u + (1.f - __cosf(twoa[ch] * u)) * inv2b[ch]) : 0.f;
        }
    }
    float xw[9][2];
#pragma unroll
    for (int m = 0; m < 6; ++m) { xw[m][0] = xa[6 + m][0]; xw[m][1] = xa[6 + m][1]; }
    ldx2(t0 + 8,  xw[6]);
    ldx2(t0 + 9,  xw[7]);
    ldx2(t0 + 10, xw[8]);

#pragma unroll 4
    for (int it = 0; it < ALT; ++it) {
        int t = t0 + it;
        float y[2] = {0.f, 0.f};
#pragma unroll
        for (int k = 0; k < 12; ++k) {
            y[0] += fw[k] * sr[k][0];
            y[1] += fw[k] * sr[k][1];
        }
        if (t < Tout) {
            s16x2 o; o[0] = f2b(y[0]); o[1] = f2b(y[1]);
            *(s16x2*)(ob + (size_t)t * CCH) = o;
        }
        bool ok1 = (2 * t + 7 < Ls), ok2 = (2 * t + 8 < Ls);
        float s1[2], s2[2];
#pragma unroll
        for (int ch = 0; ch < 2; ++ch) {
            float u1 = 0.f, u2 = 0.f;
#pragma unroll
            for (int m = 0; m < 6; ++m) {
                u1 += ph1[m] * xw[m][ch];
                u2 += ph0[m] * xw[m + 1][ch];
            }
            s1[ch] = ok1 ? (u1 + (1.f - __cosf(twoa[ch] * u1)) * inv2b[ch]) : 0.f;
            s2[ch] = ok2 ? (u2 + (1.f - __cosf(twoa[ch] * u2)) * inv2b[ch]) : 0.f;
        }
#pragma unroll
        for (int i = 0; i < 10; ++i) { sr[i][0] = sr[i + 2][0]; sr[i][1] = sr[i + 2][1]; }
        sr[10][0] = s1[0]; sr[10][1] = s1[1];
        sr[11][0] = s2[0]; sr[11][1] = s2[1];
#pragma unroll
        for (int m = 0; m < 8; ++m) { xw[m][0] = xw[m + 1][0]; xw[m][1] = xw[m + 1][1]; }
        ldx2(t + 11, xw[8]);   // 3-iteration prefetch distance
    }
}

// ---------------------------------------------------------------------------
// MFMA conv1d (k=3, pad=1) on t-major bf16 input — the measured-best R1
// structure (gload_lds dbuf staging, issue-at-top / drain-at-end, one
// __syncthreads per cc, 128co x 128t, 2 blocks/CU), with ONE change:
//
// XCD-AFFINE BLOCK MAPPING (T1): logical = (bx&7)*32 + (bx>>3).
// Dispatch round-robins bx across the 8 XCDs, so this places logicals
// [32*x, 32*x+31] (= 8 t-tiles x 4 cogs) on XCD x, all co-resident.
// The 4 cog-blocks sharing a t-tile's input now hit the SAME per-XCD L2
// (working set 8 tiles x 133KB = 1.1MB << 4MB), converting ~3/4 of input
// staging reads from L3/HBM misses (~600-900cy) to L2 hits (~200cy) and
// cutting input HBM fetch ~4x.  Bijective on [0,256) per batch.
// ---------------------------------------------------------------------------
template <int MODE>
__global__ __launch_bounds__(256) void conv_mfma(
    const short* __restrict__ xin, const short* __restrict__ wp,
    const float* __restrict__ bias, const float* __restrict__ resid,
    float* __restrict__ outF, short* __restrict__ outT, int rows)
{
    constexpr int WB = 3 * 128 * 32;   // shorts (24576 B)
    constexpr int IB = 132 * 32;       // shorts (8448 B)
    __shared__ __align__(16) short lds[2 * (WB + IB)];   // 66048 B -> 2 blocks/CU

    int tid = threadIdx.x;
    int wave = tid >> 6, lane = tid & 63;
    int quad = lane >> 4, l16 = lane & 15;
    int wm = wave >> 1, wn = wave & 1;
    int bx = blockIdx.x;
    int logical = (bx & 7) * 32 + (bx >> 3);   // XCD-affine bijection
    int cog = logical & 3, tt = logical >> 2;
    int t0 = tt * 128, b = blockIdx.z;

    const short* inb = xin + (size_t)b * RPITCH;
    bool interior = (t0 >= 1) && (t0 + 129 <= rows);

    auto stage = [&](int cc, int pb) {
        short* base = lds + pb * (WB + IB);
        short* wl = base;
        short* il = base + WB;
        const short* wsrc = wp + (size_t)(cc * 4 + cog) * WB;
#pragma unroll
        for (int p = 0; p < 6; ++p) {
            int seg = wave * 6 + p;
            glds16(wsrc + seg * 512 + lane * 8, wl + seg * 512);
        }
        const short* isrc = inb + (size_t)(t0 - 1) * CCH + cc * 32;
        if (interior) {
#pragma unroll
            for (int p = 0; p < 2; ++p) {
                int seg0 = (p * 4 + wave) * 64;
                int s = seg0 + lane;            // linear physical 16B slot
                int u = s ^ ((s >> 3) & 3);     // logical slot (inverse swizzle)
                glds16(isrc + (size_t)(u >> 2) * CCH + (u & 3) * 8, il + seg0 * 8);
            }
            if (wave == 0 && lane < 8) {
                int s = 512 + lane;             // (s>>3)&3==0: no swizzle here
                glds16(isrc + (size_t)(s >> 2) * CCH + (s & 3) * 8, il + 512 * 8);
            }
        } else {
            for (int s = tid; s < 520; s += 256) {
                int gt = t0 - 1 + (s >> 2);
                s16x8 v = 0;
                if (gt >= 0 && gt < rows)
                    v = *(const s16x8*)(inb + (size_t)gt * CCH + cc * 32 + (s & 3) * 8);
                int ps = s ^ ((s >> 3) & 3);    // store to swizzled physical slot
                *(s16x8*)(il + ps * 8) = v;
            }
        }
    };

    f32x4 acc[4][4];
#pragma unroll
    for (int i = 0; i < 4; ++i)
#pragma unroll
        for (int j = 0; j < 4; ++j) acc[i][j] = 0.f;

    stage(0, 0);
    __syncthreads();

    for (int cc = 0; cc < 16; ++cc) {
        int pb = cc & 1;
        if (cc < 15) stage(cc + 1, pb ^ 1);
        const short* base = lds + pb * (WB + IB);
        const short* wl = base;
        const short* il = base + WB;
#pragma unroll
        for (int tap = 0; tap < 3; ++tap) {
            s16x8 af[4], bv[4];
#pragma unroll
            for (int mf = 0; mf < 4; ++mf) {
                int row = wm * 64 + mf * 16 + l16;
                int off = (quad * 8) ^ (((row >> 1) & 3) << 3);
                af[mf] = *(const s16x8*)(wl + tap * 4096 + row * 32 + off);
            }
#pragma unroll
            for (int nf = 0; nf < 4; ++nf) {
                int row = wn * 64 + nf * 16 + l16 + tap;
                int off = (quad * 8) ^ (((row >> 1) & 3) << 3);
                bv[nf] = *(const s16x8*)(il + row * 32 + off);
            }
#pragma unroll
            for (int mf = 0; mf < 4; ++mf)
#pragma unroll
                for (int nf = 0; nf < 4; ++nf)
                    acc[mf][nf] = __builtin_amdgcn_mfma_f32_16x16x32_bf16(
                        af[mf], bv[nf], acc[mf][nf], 0, 0, 0);
        }
        __syncthreads();
    }

    f32x4 b4[4];
#pragma unroll
    for (int mf = 0; mf < 4; ++mf)
        b4[mf] = *(const f32x4*)(bias + cog * 128 + wm * 64 + mf * 16 + quad * 4);

    if (MODE == 0) {
        // Stage bf16 tile [t 128][co 128] (pitch 136) then coalesced stores.
        short* ot = lds;
#pragma unroll
        for (int mf = 0; mf < 4; ++mf)
#pragma unroll
            for (int nf = 0; nf < 4; ++nf) {
                int t = wn * 64 + nf * 16 + l16;
                int co = wm * 64 + mf * 16 + quad * 4;
                s16x4 o;
#pragma unroll
                for (int r = 0; r < 4; ++r) o[r] = f2b(acc[mf][nf][r] + b4[mf][r]);
                *(s16x4*)(ot + t * 136 + co) = o;
            }
        __syncthreads();
#pragma unroll
        for (int rr = 0; rr < 8; ++rr) {
            int idx = rr * 256 + tid;
            int tr = idx >> 4, c8 = (idx & 15) * 8;
            int t = t0 + tr;
            if (t < rows)
                *(s16x8*)(outT + (size_t)b * RPITCH + (size_t)t * CCH + cog * 128 + c8)
                    = *(const s16x8*)(ot + tr * 136 + c8);
        }
    } else {
        // Two halves of fp32 [co 64][t 128] (pitch 132), +bias then +residual.
        float* of = (float*)lds;
#pragma unroll
        for (int h = 0; h < 2; ++h) {
            if (wm == h) {
#pragma unroll
                for (int mf = 0; mf < 4; ++mf)
#pragma unroll
                    for (int nf = 0; nf < 4; ++nf) {
                        int t = wn * 64 + nf * 16 + l16;
#pragma unroll
                        for (int r = 0; r < 4; ++r)
                            of[(mf * 16 + quad * 4 + r) * 132 + t] = acc[mf][nf][r] + b4[mf][r];
                    }
            }
            __syncthreads();
#pragma unroll
            for (int rr = 0; rr < 8; ++rr) {
                int idx = rr * 256 + tid;
                int row = idx >> 5, c4 = (idx & 31) * 4;
                int co = cog * 128 + h * 64 + row;
                int t = t0 + c4;
                f32x4 v = *(const f32x4*)(of + row * 132 + c4);
                size_t ro = (size_t)b * CCH + co;
                const float* rrow = resid + ro * TLEN;
                float* orow = outF + ro * (size_t)rows;
                if (t + 3 < rows) {
                    f32x4 rv = *(const f32x4*)(rrow + t);
                    f32x4 ov;
#pragma unroll
                    for (int i = 0; i < 4; ++i) ov[i] = v[i] + rv[i];
                    *(f32x4*)(orow + t) = ov;
                } else {
#pragma unroll
                    for (int i = 0; i < 4; ++i)
                        if (t + i < rows) orow[t + i] = v[i] + rrow[t + i];
                }
            }
            __syncthreads();
        }
    }
}

// ---------------------------------------------------------------------------
extern "C" void kernel_launch(void* const* d_in, const int* in_sizes, int n_in,
                              void* d_out, int out_size, void* d_ws, size_t ws_size,
                              hipStream_t stream)
{
    const float* x      = (const float*)d_in[0];
    const float* alpha1 = (const float*)d_in[1];
    const float* beta1  = (const float*)d_in[2];
    const float* alpha2 = (const float*)d_in[3];
    const float* beta2  = (const float*)d_in[4];
    const float* v1     = (const float*)d_in[5];
    const float* g1     = (const float*)d_in[6];
    const float* b1     = (const float*)d_in[7];
    const float* v2     = (const float*)d_in[8];
    const float* g2     = (const float*)d_in[9];
    const float* b2     = (const float*)d_in[10];
    const float* upf    = (const float*)d_in[11];
    const float* dwf    = (const float*)d_in[12];
    float* out = (float*)d_out;

    const int T1 = TLEN - 2;  // 8190
    const int T2 = TLEN - 4;  // 8188

    char* wsb = (char*)d_ws;
    short* w1p = (short*)wsb;
    short* w2p = w1p + (size_t)CCH * CCH * 3;
    short* bufX = w2p + (size_t)CCH * CCH * 3;
    short* bufY = bufX + (size_t)BATCH * RPITCH;

    wn_pack_kernel<<<CCH, 256, 0, stream>>>(v1, g1, w1p);
    wn_pack_kernel<<<CCH, 256, 0, stream>>>(v2, g2, w2p);

    transpose_kernel2<<<dim3(TLEN / 64, CCH / 64, BATCH), 256, 0, stream>>>(x, bufX);

    act_kernel<<<dim3((TLEN + ALT - 1) / ALT, 1, BATCH), 256, 0, stream>>>(
        bufX, bufY, alpha1, beta1, upf, dwf, TLEN, T1);

    conv_mfma<0><<<dim3(256, 1, BATCH), 256, 0, stream>>>(
        bufY, w1p, b1, nullptr, nullptr, bufX, T1);

    act_kernel<<<dim3((T1 + ALT - 1) / ALT, 1, BATCH), 256, 0, stream>>>(
        bufX, bufY, alpha2, beta2, upf, dwf, T1, T2);

    conv_mfma<1><<<dim3(256, 1, BATCH), 256, 0, stream>>>(
        bufY, w2p, b2, x, out, nullptr, T2);
}